// Round 7
// baseline (825.334 us; speedup 1.0000x reference)
//
#include <hip/hip_runtime.h>

#define BS 256       // 4 waves/block; each wave owns 128 points (2/thread). Zero barriers.
#define NFEAT 121
#define SST 37       // LDS row stride (floats), odd -> conflict-free.
                     // slab/wave = 128*37*4 = 18,944 B; block = 75,776 B -> 2 blocks/CU.

// 2 points per thread: ptA = tile+lane, ptB = tile+64+lane. Both accumulator chains
// run interleaved in the same rolled j-loop -> each coefficient s_load is amortized
// over 2x the FMAs and the wave has 2 independent dep streams. unroll 2 lets the
// compiler prefetch iteration j+1's coefficients during j's FMAs (SMEM pipelining).
// 4 column phases: A f0..f5 [0,36)  B f6,f7 [36,64)  C f8,f9 [64,100)  D f10 [100,121)

__device__ __forceinline__ float dot3(const float* __restrict__ c, float x, float y, float z) {
    return fmaf(c[2], z, fmaf(c[1], y, c[0] * x));
}

template<int LL, bool UPD>
__device__ __forceinline__ void step2(const float* __restrict__ cob,
                                      float* srowA, float* srowB, int colofs,
                                      float ax, float ay, float az,
                                      float bx, float by, float bz,
                                      float* prevA, float* prevB) {
    constexpr int IN  = 2 * LL - 1;
    constexpr int OUT = 2 * LL + 1;
    #pragma unroll 2
    for (int j = 0; j < OUT; ++j) {
        const float* __restrict__ crow = cob + j * (3 * IN);  // wave-uniform -> s_load
        float accA = 0.f, accB = 0.f;
        #pragma unroll
        for (int a = 0; a < IN; ++a) {
            const float c0 = crow[3*a+0], c1 = crow[3*a+1], c2 = crow[3*a+2];
            accA = fmaf(prevA[a], fmaf(c2, az, fmaf(c1, ay, c0 * ax)), accA);
            accB = fmaf(prevB[a], fmaf(c2, bz, fmaf(c1, by, c0 * bx)), accB);
        }
        srowA[colofs + j] = accA;
        srowB[colofs + j] = accB;
    }
    if (UPD) {
        #pragma unroll
        for (int j = 0; j < OUT; ++j) {
            prevA[j] = srowA[colofs + j];
            prevB[j] = srowB[colofs + j];
        }
    }
}

// Per-wave drain: lanes 0..W-1 each own a column over the wave's 128 staged rows.
// Addresses advance by compile-time constants; stores are runs of W consecutive
// floats per output row. No barrier: same-wave LDS ops are in-order and the slab
// aliasing (srowA/srowB vs slab, all from sbuf) stays visible to the compiler.
template<int W, int C0>
__device__ __forceinline__ void wave_drain(const float* slab, float* __restrict__ outw,
                                           int wrows, int lane) {
    if (lane < W) {
        const float* sp = slab + lane;
        float* __restrict__ gp = outw + C0 + lane;
        if (wrows == 128) {
            #pragma unroll 16
            for (int r = 0; r < 128; ++r)
                gp[r * NFEAT] = sp[r * SST];
        } else {
            #pragma unroll 4
            for (int r = 0; r < 128; ++r)
                if (r < wrows) gp[r * NFEAT] = sp[r * SST];
        }
    }
}

__global__ __launch_bounds__(BS) void harmonic_kernel(
    const float* __restrict__ points,
    const float* __restrict__ cob1,  const float* __restrict__ cob2,
    const float* __restrict__ cob3,  const float* __restrict__ cob4,
    const float* __restrict__ cob5,  const float* __restrict__ cob6,
    const float* __restrict__ cob7,  const float* __restrict__ cob8,
    const float* __restrict__ cob9,  const float* __restrict__ cob10,
    float* __restrict__ out, int N) {
    __shared__ float sbuf[(BS / 64) * 128 * SST];   // 75,776 B -> 2 blocks/CU

    const int t    = threadIdx.x;
    const int lane = t & 63;
    const int w    = t >> 6;
    const long long wtile = (long long)blockIdx.x * ((BS / 64) * 128) + (long long)w * 128;
    const long long pA = wtile + lane;
    const long long pB = wtile + 64 + lane;
    long long nv = (long long)N - wtile;
    const int wrows = nv >= 128 ? 128 : (nv > 0 ? (int)nv : 0);

    float pax = 0.f, pay = 0.f, paz = 0.f, pbx = 0.f, pby = 0.f, pbz = 0.f;
    if (pA < (long long)N) {
        pax = points[pA * 3 + 0]; pay = points[pA * 3 + 1]; paz = points[pA * 3 + 2];
    }
    if (pB < (long long)N) {
        pbx = points[pB * 3 + 0]; pby = points[pB * 3 + 1]; pbz = points[pB * 3 + 2];
    }

    const float ax = dot3(cob1 + 0, pax, pay, paz);
    const float ay = dot3(cob1 + 3, pax, pay, paz);
    const float az = dot3(cob1 + 6, pax, pay, paz);
    const float bx = dot3(cob1 + 0, pbx, pby, pbz);
    const float by = dot3(cob1 + 3, pbx, pby, pbz);
    const float bz = dot3(cob1 + 6, pbx, pby, pbz);

    float prevA[21], prevB[21];
    prevA[0] = ax; prevA[1] = ay; prevA[2] = az;
    prevB[0] = bx; prevB[1] = by; prevB[2] = bz;

    float* slab  = sbuf + w * (128 * SST);      // this wave's 128-row slab
    float* srowA = slab + lane * SST;           // ptA: rows 0..63
    float* srowB = slab + (64 + lane) * SST;    // ptB: rows 64..127
    float* __restrict__ outw = out + wtile * NFEAT;

    // ---- Phase A: f0..f5 -> cols [0,36) ----
    srowA[0] = 1.f; srowA[1] = ax; srowA[2] = ay; srowA[3] = az;
    srowB[0] = 1.f; srowB[1] = bx; srowB[2] = by; srowB[3] = bz;
    step2<2, true>(cob2, srowA, srowB, 4,  ax, ay, az, bx, by, bz, prevA, prevB);
    step2<3, true>(cob3, srowA, srowB, 9,  ax, ay, az, bx, by, bz, prevA, prevB);
    step2<4, true>(cob4, srowA, srowB, 16, ax, ay, az, bx, by, bz, prevA, prevB);
    step2<5, true>(cob5, srowA, srowB, 25, ax, ay, az, bx, by, bz, prevA, prevB);
    wave_drain<36, 0>(slab, outw, wrows, lane);

    // ---- Phase B: f6,f7 -> cols [36,64) ----
    step2<6, true>(cob6, srowA, srowB, 0,  ax, ay, az, bx, by, bz, prevA, prevB);
    step2<7, true>(cob7, srowA, srowB, 13, ax, ay, az, bx, by, bz, prevA, prevB);
    wave_drain<28, 36>(slab, outw, wrows, lane);

    // ---- Phase C: f8,f9 -> cols [64,100) ----
    step2<8, true>(cob8, srowA, srowB, 0,  ax, ay, az, bx, by, bz, prevA, prevB);
    step2<9, true>(cob9, srowA, srowB, 17, ax, ay, az, bx, by, bz, prevA, prevB);
    wave_drain<36, 64>(slab, outw, wrows, lane);

    // ---- Phase D: f10 -> cols [100,121) ----
    step2<10, false>(cob10, srowA, srowB, 0, ax, ay, az, bx, by, bz, prevA, prevB);
    wave_drain<21, 100>(slab, outw, wrows, lane);
}

extern "C" void kernel_launch(void* const* d_in, const int* in_sizes, int n_in,
                              void* d_out, int out_size, void* d_ws, size_t ws_size,
                              hipStream_t stream) {
    const float* points = (const float*)d_in[0];
    const float* cob[10];
    for (int i = 0; i < 10; ++i) cob[i] = (const float*)d_in[1 + i];
    float* out = (float*)d_out;
    const int N = in_sizes[0] / 3;

    const int ptsPerBlock = (BS / 64) * 128;   // 512
    const int grid = (N + ptsPerBlock - 1) / ptsPerBlock;
    harmonic_kernel<<<grid, BS, 0, stream>>>(
        points,
        cob[0], cob[1], cob[2], cob[3], cob[4],
        cob[5], cob[6], cob[7], cob[8], cob[9],
        out, N);
}